// Round 5
// baseline (111.554 us; speedup 1.0000x reference)
//
#include <hip/hip_runtime.h>

// RoPE with on-the-fly trig (no sin/cos table loads) and explicit software
// pipelining: iteration t+1's pos + x loads are issued BEFORE iteration t's
// trans chain + store, so each wave keeps bytes outstanding during the
// dependent compute. 8 floats (2 x float4) per thread per iteration.
// Compulsory traffic: 256 MB read + 256 MB write + 2 MB pos -> ~82 us floor.

typedef float f32x4 __attribute__((ext_vector_type(4)));

__global__ __launch_bounds__(256)
void rope_kernel(const float* __restrict__ x,
                 const int* __restrict__ pos,
                 float* __restrict__ out,
                 int n8) {
    int idx = blockIdx.x * blockDim.x + threadIdx.x;
    int stride = gridDim.x * blockDim.x;   // 524288; n8/stride = 16 exact iters
    const float K = 0.20762051f;           // log2(10000)/64
    const float INV2PI = 0.15915494309189535f;
    int i0 = (idx & 15) << 2;              // first pair index: 0,4,...,60 (loop-invariant)
    float ifr0 = exp2f(-(float)(i0    ) * K) * INV2PI;
    float ifr1 = exp2f(-(float)(i0 + 1) * K) * INV2PI;
    float ifr2 = exp2f(-(float)(i0 + 2) * K) * INV2PI;
    float ifr3 = exp2f(-(float)(i0 + 3) * K) * INV2PI;

    int g = idx;
    if (g >= n8) return;
    // prologue: first iteration's loads
    int p = pos[g >> 4];
    const f32x4* xp = reinterpret_cast<const f32x4*>(x) + 2ll * g;
    f32x4 v0 = xp[0];
    f32x4 v1 = xp[1];

    while (true) {
        int gn = g + stride;
        bool more = gn < n8;               // uniform across the grid (exact multiple)
        int pn = 0;
        f32x4 w0, w1;
        if (more) {                        // prefetch next iteration FIRST
            pn = pos[gn >> 4];
            const f32x4* xpn = reinterpret_cast<const f32x4*>(x) + 2ll * gn;
            w0 = xpn[0];
            w1 = xpn[1];
        }
        // compute current iteration (pos-dependent trans chain)
        float pf = (float)p;
        float a0 = __builtin_amdgcn_fractf(pf * ifr0);
        float a1 = __builtin_amdgcn_fractf(pf * ifr1);
        float a2 = __builtin_amdgcn_fractf(pf * ifr2);
        float a3 = __builtin_amdgcn_fractf(pf * ifr3);
        float s0 = __builtin_amdgcn_sinf(a0), c0 = __builtin_amdgcn_cosf(a0);
        float s1 = __builtin_amdgcn_sinf(a1), c1 = __builtin_amdgcn_cosf(a1);
        float s2 = __builtin_amdgcn_sinf(a2), c2 = __builtin_amdgcn_cosf(a2);
        float s3 = __builtin_amdgcn_sinf(a3), c3 = __builtin_amdgcn_cosf(a3);
        f32x4 r0, r1;
        r0.x = c0 * v0.x - s0 * v0.y;  r0.y = s0 * v0.x + c0 * v0.y;
        r0.z = c1 * v0.z - s1 * v0.w;  r0.w = s1 * v0.z + c1 * v0.w;
        r1.x = c2 * v1.x - s2 * v1.y;  r1.y = s2 * v1.x + c2 * v1.y;
        r1.z = c3 * v1.z - s3 * v1.w;  r1.w = s3 * v1.z + c3 * v1.w;
        f32x4* op = reinterpret_cast<f32x4*>(out) + 2ll * g;
        op[0] = r0;
        op[1] = r1;
        if (!more) break;
        g = gn; p = pn; v0 = w0; v1 = w1;
    }
}

extern "C" void kernel_launch(void* const* d_in, const int* in_sizes, int n_in,
                              void* d_out, int out_size, void* d_ws, size_t ws_size,
                              hipStream_t stream) {
    const float* x   = (const float*)d_in[0];
    const int*   pos = (const int*)d_in[3];
    float* out = (float*)d_out;

    int n8 = out_size / 8;                 // 8,388,608 chunks of 8 floats
    const int block = 256;
    int grid = 2048;                       // 8 waves/SIMD exactly; 16 iters/thread
    rope_kernel<<<grid, block, 0, stream>>>(x, pos, out, n8);
}

// Round 6
// 95.380 us; speedup vs baseline: 1.1696x; 1.1696x over previous
//
#include <hip/hip_runtime.h>

// RoPE with on-the-fly trig, MONOLITHIC launch: one thread per float4,
// 65536 blocks x 256 threads, no grid-stride loop. Every wave issues its
// load immediately at birth and retires after one store; block-level
// parallelism (256 blocks queued per CU) replaces loop-level latency
// hiding. Body identical to round-4 kernel.
// Compulsory traffic: 256 MB read + 256 MB write + 2 MB pos -> ~82 us floor
// at the 6.3 TB/s measured copy ceiling.

typedef float f32x4 __attribute__((ext_vector_type(4)));

__global__ __launch_bounds__(256)
void rope_kernel(const float* __restrict__ x,
                 const int* __restrict__ pos,
                 float* __restrict__ out) {
    int g = blockIdx.x * 256 + threadIdx.x;   // one float4 group per thread
    int row = g >> 5;                         // 32 float4 groups per 128-elem row
    int p = pos[row];                         // issue ASAP; bcast across 32 lanes
    const f32x4 v = *reinterpret_cast<const f32x4*>(x + 4ll * g);

    const float K = 0.20762051f;              // log2(10000)/64
    const float INV2PI = 0.15915494309189535f;
    int i0 = (g & 31) << 1;                   // frequency index of first pair
    float ifr0 = exp2f(-(float)i0 * K) * INV2PI;        // overlaps the pos/x loads
    float ifr1 = exp2f(-(float)(i0 + 1) * K) * INV2PI;

    float pf = (float)p;
    float a0 = __builtin_amdgcn_fractf(pf * ifr0);      // revolutions in [0,1)
    float a1 = __builtin_amdgcn_fractf(pf * ifr1);
    float s0 = __builtin_amdgcn_sinf(a0);
    float c0 = __builtin_amdgcn_cosf(a0);
    float s1 = __builtin_amdgcn_sinf(a1);
    float c1 = __builtin_amdgcn_cosf(a1);

    f32x4 r;
    r.x = c0 * v.x - s0 * v.y;
    r.y = s0 * v.x + c0 * v.y;
    r.z = c1 * v.z - s1 * v.w;
    r.w = s1 * v.z + c1 * v.w;
    *reinterpret_cast<f32x4*>(out + 4ll * g) = r;
}

extern "C" void kernel_launch(void* const* d_in, const int* in_sizes, int n_in,
                              void* d_out, int out_size, void* d_ws, size_t ws_size,
                              hipStream_t stream) {
    const float* x   = (const float*)d_in[0];
    const int*   pos = (const int*)d_in[3];
    float* out = (float*)d_out;

    int n4 = out_size / 4;                 // 16,777,216 float4 groups
    const int block = 256;
    int grid = n4 / block;                 // 65536 blocks, exact
    rope_kernel<<<grid, block, 0, stream>>>(x, pos, out);
}